// Round 1
// baseline (242.397 us; speedup 1.0000x reference)
//
#include <hip/hip_runtime.h>
#include <stdint.h>

// ---------------------------------------------------------------------------
// QConv1d fake-quant hardware simulation.
//   x: (4,16,2048) f32, weight: (64,16,7) f32, table: (61,1000) f32
//   out: (4,64,2042) f32
//
// PRNG_MODE 0: JAX threefry "partitionable" (default since jax 0.4.30):
//   split fold-like: k_i = tf(key,(0,i)); bits32[i] = o0^o1 of tf(k,(0,i))
// PRNG_MODE 1: legacy "original": split via iota(4) packing; bits via
//   concat(out0,out1) of tf(k,(j, j+half)).
// Flip the macro if absmax comes back O(1..15) (wrong random stream).
// ---------------------------------------------------------------------------
#define PRNG_MODE 0

#define NELEM_TOT 43911168u  // 84 * 8168 * 64
#define RSTRIDE   522752u    // 8168 * 64
#define LOUT 2042
#define CO   64
#define CIN  16
#define LIN  2048
#define KW   7
#define DTOT 112             // CIN*KW
#define WSTR 116             // padded LDS stride (29 dwords, coprime with 32 banks)

__host__ __device__ __forceinline__ void tf2x32(uint32_t k0, uint32_t k1,
                                                uint32_t x0, uint32_t x1,
                                                uint32_t& o0, uint32_t& o1) {
  uint32_t ks2 = k0 ^ k1 ^ 0x1BD11BDAu;
  x0 += k0; x1 += k1;
#define TFR(r) { x0 += x1; x1 = (x1 << (r)) | (x1 >> (32 - (r))); x1 ^= x0; }
  TFR(13) TFR(15) TFR(26) TFR(6)
  x0 += k1;  x1 += ks2 + 1u;
  TFR(17) TFR(29) TFR(16) TFR(24)
  x0 += ks2; x1 += k0 + 2u;
  TFR(13) TFR(15) TFR(26) TFR(6)
  x0 += k0;  x1 += k1 + 3u;
  TFR(17) TFR(29) TFR(16) TFR(24)
  x0 += k1;  x1 += ks2 + 4u;
  TFR(13) TFR(15) TFR(26) TFR(6)
  x0 += ks2; x1 += k0 + 5u;
#undef TFR
  o0 = x0; o1 = x1;
}

__device__ __forceinline__ uint32_t randbits32(uint32_t ka, uint32_t kb, uint32_t i) {
#if PRNG_MODE == 0
  uint32_t o0, o1;
  tf2x32(ka, kb, 0u, i, o0, o1);
  return o0 ^ o1;
#else
  const uint32_t half = NELEM_TOT / 2u;
  uint32_t j = (i < half) ? i : (i - half);
  uint32_t o0, o1;
  tf2x32(ka, kb, j, j + half, o0, o1);
  return (i < half) ? o0 : o1;
#endif
}

__global__ __launch_bounds__(256) void qconv1d_kernel(
    const float* __restrict__ x, const float* __restrict__ w,
    const float* __restrict__ table, float* __restrict__ out,
    uint32_t k1a, uint32_t k1b, uint32_t k2a, uint32_t k2b) {
  // LDS
  __shared__ int8_t  w2[3 * 64 * WSTR];   // 2*{q_plus, q_minus_low, q_minus_high}
  __shared__ uint8_t xr[4][DTOT];         // x_int rows (6..14)
  __shared__ float   y15lut[841];         // (y2*0.5)/15, y2 in [-448, 392]
  __shared__ float   biasv[64];
  __shared__ int     bias_i[64];

  const int tid = threadIdx.x;
  if (tid < 64) bias_i[tid] = 0;
  __syncthreads();

  // ---- stage quantized weights: iw = rint(clip(w,-2,1.75)*4) in [-8,7] ----
  for (int task = tid; task < 64 * 28; task += 256) {
    int c = task / 28, q = task % 28, d0 = q * 4;
    uint32_t pp = 0, pl = 0, ph = 0;
    int siw = 0;
#pragma unroll
    for (int k = 0; k < 4; ++k) {
      float wv = w[c * DTOT + d0 + k];
      float wc = fminf(fmaxf(wv, -2.0f), 1.75f);
      int iw = (int)rintf(wc * 4.0f);
      siw += iw;
      int p  = iw > 0 ? iw : 0;                    // 2*q_plus
      int mh = (-iw - 2) > 0 ? (-iw - 2) : 0;      // 2*q_minus_high
      int ml = (iw < 0 ? -iw : 0) - 2 * mh;        // 2*q_minus_low
      pp |= (uint32_t)(p  & 0xff) << (8 * k);
      pl |= (uint32_t)(ml & 0xff) << (8 * k);
      ph |= (uint32_t)(mh & 0xff) << (8 * k);
    }
    int off = c * WSTR + d0;
    *(uint32_t*)&w2[0 * 64 * WSTR + off] = pp;
    *(uint32_t*)&w2[1 * 64 * WSTR + off] = pl;
    *(uint32_t*)&w2[2 * 64 * WSTR + off] = ph;
    atomicAdd(&bias_i[c], siw);
  }

  // ---- stage x_int rows: x_int = 2*rint(clip(x)*4) + 6 in {6..14} ----
  const int r0 = blockIdx.x * 4;
  for (int idx = tid; idx < 4 * DTOT; idx += 256) {
    int row = idx / DTOT, d = idx - row * DTOT;
    int cin = d / KW, kk = d - cin * KW;
    int r = r0 + row, b = r / LOUT, l = r - b * LOUT;
    float xv = x[(b * CIN + cin) * LIN + l + kk];
    float xc = fminf(fmaxf(xv, -2.0f), 1.75f);
    xr[row][d] = (uint8_t)(2 * (int)rintf(xc * 4.0f) + 6);
  }

  // ---- y15 LUT: exact IEEE y/15 for every possible y (y2 = 2*y) ----
  for (int i = tid; i < 841; i += 256) {
    y15lut[i] = ((float)(i - 448) * 0.5f) / 15.0f;
  }
  __syncthreads();
  if (tid < 64) biasv[tid] = 3.0f * (float)bias_i[tid];  // == 6*sum(q_int)
  __syncthreads();

  // ---- main: one thread per (r, c) output ----
  const int rl = tid >> 6, c = tid & 63;
  const int r = r0 + rl;
  const uint8_t* xrow = xr[rl];
  const int8_t*  wrow = &w2[c * WSTR];
  const uint32_t base = (uint32_t)r * 64u + (uint32_t)c;

  float acc = 0.0f;
  const float S15[3] = {15.0f, -15.0f, -30.0f};

  for (int t = 0; t < 3; ++t) {
    const float s = S15[t];
    const int8_t* wt = wrow + t * (64 * WSTR);
    const uint32_t ib = base + (uint32_t)t * 28u * RSTRIDE;
#pragma unroll 2
    for (int g = 0; g < 28; ++g) {
      uint32_t i = ib + (uint32_t)g * RSTRIDE;     // flat C-order index (t,g,r,c)
      uint32_t hi = randbits32(k1a, k1b, i);
      uint32_t lo = randbits32(k2a, k2b, i);
      // randint combine: ((hi%span)*((2^16%span)^2%span) + lo%span) % span
      uint32_t rnd = ((hi % 1000u) * 296u + lo % 1000u) % 1000u;

      uint32_t xw = *(const uint32_t*)(xrow + g * 4);
      uint32_t ww = *(const uint32_t*)(wt + g * 4);
      int y2 = 0;
#pragma unroll
      for (int k = 0; k < 4; ++k) {
        int xbk = (int)((xw >> (8 * k)) & 0xffu);
        int wbk = (int)((int32_t)(ww << (24 - 8 * k)) >> 24);
        y2 += xbk * wbk;
      }
      int yidx = y2 > 0 ? (y2 >> 1) : 0;           // trunc toward zero, clip low
      yidx = yidx < 60 ? yidx : 60;                // clip high
      float y15 = y15lut[y2 + 448];
      float gv  = table[yidx * 1000 + (int)rnd];
      float res = (gv + y15) - y15;                // match ref rounding exactly
      acc = fmaf(s, res, acc);
    }
  }

  const int b = r / LOUT, l = r - b * LOUT;
  float v = (acc - biasv[c]) * 0.0625f;            // /16 exact
  v = fminf(fmaxf(v, -8.0f), 7.75f);
  out[(b * CO + c) * LOUT + l] = rintf(v * 4.0f) * 0.25f;  // fake_quant(.,2,6)
}

extern "C" void kernel_launch(void* const* d_in, const int* in_sizes, int n_in,
                              void* d_out, int out_size, void* d_ws, size_t ws_size,
                              hipStream_t stream) {
  const float* x     = (const float*)d_in[0];
  const float* w     = (const float*)d_in[1];
  const float* table = (const float*)d_in[2];
  float* out = (float*)d_out;

  // Derive the two randint subkeys from jax.random.key(1234) = (0, 1234) on host.
  uint32_t k1a, k1b, k2a, k2b;
#if PRNG_MODE == 0
  // fold-like split: k_i = tf(key, (0, i))
  tf2x32(0u, 1234u, 0u, 0u, k1a, k1b);
  tf2x32(0u, 1234u, 0u, 1u, k2a, k2b);
#else
  // original split: counts [0,1,2,3] -> x0=[0,1], x1=[2,3]
  uint32_t e0a, e0b, e1a, e1b;
  tf2x32(0u, 1234u, 0u, 2u, e0a, e0b);
  tf2x32(0u, 1234u, 1u, 3u, e1a, e1b);
  k1a = e0a; k1b = e1a; k2a = e0b; k2b = e1b;
#endif

  qconv1d_kernel<<<dim3(2042), dim3(256), 0, stream>>>(x, w, table, out,
                                                       k1a, k1b, k2a, k2b);
}